// Round 13
// baseline (164.554 us; speedup 1.0000x reference)
//
#include <hip/hip_runtime.h>

#define POOL_S 8
#define BINB 9
#define MAXPB 3584
#define EPB 2048

typedef __bf16 bf16x8 __attribute__((ext_vector_type(8)));
typedef float f32x4 __attribute__((ext_vector_type(4)));
typedef int intx4 __attribute__((ext_vector_type(4)));

__device__ __forceinline__ unsigned short f2bf(float f) {
    unsigned u = __float_as_uint(f);
    unsigned r = u + 0x7FFFu + ((u >> 16) & 1u);
    return (unsigned short)(r >> 16);
}
__device__ __forceinline__ float bflo(unsigned u) { return __uint_as_float(u << 16); }
__device__ __forceinline__ float bfhi(unsigned u) { return __uint_as_float(u & 0xFFFF0000u); }

// ---------------- W pre-pack ----------------

__device__ __forceinline__ void prepW_one(const float* __restrict__ W, uint4* __restrict__ Wp, int t) {
    int slot = t >> 6, lane = t & 63;
    int nt = slot >> 2, kt = slot & 3;
    int kbase = kt * 32 + (lane >> 4) * 8;
    int colw = nt * 16 + (lane & 15);
    unsigned short e[8];
#pragma unroll
    for (int j = 0; j < 8; ++j) e[j] = f2bf(W[(kbase + j) * 128 + colw]);
    uint4 v;
    v.x = e[0] | ((unsigned)e[1] << 16);
    v.y = e[2] | ((unsigned)e[3] << 16);
    v.z = e[4] | ((unsigned)e[5] << 16);
    v.w = e[6] | ((unsigned)e[7] << 16);
    Wp[t] = v;
}

__global__ __launch_bounds__(256) void k_prep(const float* __restrict__ W1, const float* __restrict__ W2,
                                              uint4* __restrict__ wp1, uint4* __restrict__ wp2,
                                              int* degi, int* binFillR, int* binFillC, int n) {
    int i = blockIdx.x * 256 + threadIdx.x;
    if (i < n) degi[i] = 0;
    if (i < 256) { binFillR[i] = 0; binFillC[i] = 0; }
    if (i < 2048) prepW_one(W1, wp1, i);
    else if (i < 4096) prepW_one(W2, wp2, i - 2048);
}

__global__ __launch_bounds__(256) void k_dinv(const int* __restrict__ degi, float* __restrict__ dinv, int n) {
    int i = blockIdx.x * 256 + threadIdx.x;
    if (i < n) dinv[i] = rsqrtf((float)degi[i] + 1.0f);   // +1: self loop
}

// ---------------- pass B: dual bin-scatter (rows -> CSR segs, cols -> deg segs) ----------------

__global__ __launch_bounds__(256) void k_binscat(const int* __restrict__ row, const int* __restrict__ col,
                                                 int* binFillR, int* binFillC,
                                                 unsigned* __restrict__ sortedR, unsigned short* __restrict__ sortedC,
                                                 int ne) {
    __shared__ int lhR[256], lbR[256], loR[256];
    __shared__ int lhC[256], lbC[256], loC[256];
    int t = threadIdx.x;
    lhR[t] = 0; loR[t] = 0; lhC[t] = 0; loC[t] = 0;
    __syncthreads();

    long base0 = (long)blockIdx.x * EPB + (long)t * 8;
    int r[8], c[8];
    int k = 0;
    if (base0 < ne) {
        k = (int)(ne - base0); if (k > 8) k = 8;
        if (k == 8) {
            intx4 r0 = *(const intx4*)(row + base0);
            intx4 r1 = *(const intx4*)(row + base0 + 4);
            intx4 c0 = *(const intx4*)(col + base0);
            intx4 c1 = *(const intx4*)(col + base0 + 4);
            r[0]=r0[0]; r[1]=r0[1]; r[2]=r0[2]; r[3]=r0[3];
            r[4]=r1[0]; r[5]=r1[1]; r[6]=r1[2]; r[7]=r1[3];
            c[0]=c0[0]; c[1]=c0[1]; c[2]=c0[2]; c[3]=c0[3];
            c[4]=c1[0]; c[5]=c1[1]; c[6]=c1[2]; c[7]=c1[3];
        } else {
            for (int i = 0; i < 8; ++i) { int e = i < k ? i : 0; r[i] = row[base0 + e]; c[i] = col[base0 + e]; }
        }
#pragma unroll
        for (int i = 0; i < 8; ++i) if (i < k) {
            atomicAdd(&lhR[r[i] >> BINB], 1);
            atomicAdd(&lhC[c[i] >> BINB], 1);
        }
    }
    __syncthreads();
    if (lhR[t] > 0) lbR[t] = atomicAdd(&binFillR[t], lhR[t]);
    if (lhC[t] > 0) lbC[t] = atomicAdd(&binFillC[t], lhC[t]);
    __syncthreads();
#pragma unroll
    for (int i = 0; i < 8; ++i) if (i < k) {
        int bR = r[i] >> BINB;
        int p = lbR[bR] + atomicAdd(&loR[bR], 1);
        if (p < MAXPB) sortedR[(long)bR * MAXPB + p] = ((unsigned)(r[i] & 511) << 17) | (unsigned)c[i];
        int bC = c[i] >> BINB;
        int q = lbC[bC] + atomicAdd(&loC[bC], 1);
        if (q < MAXPB) sortedC[(long)bC * MAXPB + q] = (unsigned short)(c[i] & 511);
    }
}

// ---------------- pass C: blocks [0,nbins) build row-CSR; [nbins,2*nbins) build dinv ----------------

__global__ __launch_bounds__(256) void k_csrdeg(const unsigned* __restrict__ sortedR, const int* __restrict__ binFillR,
                                                const unsigned short* __restrict__ sortedC, const int* __restrict__ binFillC,
                                                int* __restrict__ start, int* __restrict__ cntn,
                                                int* __restrict__ csrcol, float* __restrict__ dinv,
                                                int n, int nbins) {
    __shared__ int lcnt[512];
    __shared__ int lex[512];
    __shared__ int ps[256];
    __shared__ int lcsr[MAXPB];
    int t = threadIdx.x;

    if ((int)blockIdx.x >= nbins) {
        int bc = blockIdx.x - nbins;
        lcnt[t] = 0; lcnt[t + 256] = 0;
        __syncthreads();
        int cntE = binFillC[bc]; if (cntE > MAXPB) cntE = MAXPB;
        long base = (long)bc * MAXPB;
        for (int e = t; e < cntE; e += 256) atomicAdd(&lcnt[sortedC[base + e]], 1);
        __syncthreads();
        int nd0 = (bc << BINB) + t, nd1 = nd0 + 256;
        if (nd0 < n) dinv[nd0] = rsqrtf((float)lcnt[t] + 1.0f);
        if (nd1 < n) dinv[nd1] = rsqrtf((float)lcnt[t + 256] + 1.0f);
        return;
    }

    int b = blockIdx.x;
    int node0 = b << BINB;
    int cntE = binFillR[b]; if (cntE > MAXPB) cntE = MAXPB;
    long base = (long)b * MAXPB;

    lcnt[t] = 0; lcnt[t + 256] = 0;
    __syncthreads();
    for (int e = t; e < cntE; e += 256) atomicAdd(&lcnt[sortedR[base + e] >> 17], 1);
    __syncthreads();

    int a0 = lcnt[2 * t], a1 = lcnt[2 * t + 1];
    ps[t] = a0 + a1;
    __syncthreads();
    for (int d = 1; d < 256; d <<= 1) {
        int u = (t >= d) ? ps[t - d] : 0;
        __syncthreads();
        ps[t] += u;
        __syncthreads();
    }
    int excl_pair = ps[t] - (a0 + a1);
    lex[2 * t] = excl_pair;
    lex[2 * t + 1] = excl_pair + a0;
    __syncthreads();

    int nd0 = node0 + t, nd1 = node0 + t + 256;
    if (nd0 < n) { start[nd0] = (int)base + lex[t];       cntn[nd0] = lcnt[t]; }
    if (nd1 < n) { start[nd1] = (int)base + lex[t + 256]; cntn[nd1] = lcnt[t + 256]; }
    __syncthreads();
    lcnt[t] = lex[t]; lcnt[t + 256] = lex[t + 256];
    __syncthreads();
    for (int e = t; e < cntE; e += 256) {
        unsigned pk = sortedR[base + e];
        int lr = (int)(pk >> 17);
        int pos = atomicAdd(&lcnt[lr], 1);
        lcsr[pos] = (int)(pk & 0x1FFFFu);
    }
    __syncthreads();
    for (int e = t; e < cntE; e += 256) csrcol[base + e] = lcsr[e];
}

// ---------------- GEMM: 64 rows x 128 cols per block; optional per-row scale (dinv) ----------------

template<int IN_BF16>
__global__ __launch_bounds__(256) void k_gemm_mfma(const void* __restrict__ Xv,
        const float4* __restrict__ Wp, const float* __restrict__ Bias,
        const float* __restrict__ rowscale,
        unsigned short* __restrict__ Y, int nrows) {
    __shared__ float4 Wl[2048];
    int t = threadIdx.x;
#pragma unroll
    for (int i = 0; i < 8; ++i) Wl[t + 256 * i] = Wp[t + 256 * i];
    __syncthreads();

    int wid = t >> 6, lane = t & 63;
    long m0 = ((long)blockIdx.x * 4 + wid) * 16;
    if (m0 >= nrows) return;
    int lr = lane & 15, lg = lane >> 4;
    long mr = m0 + lr; if (mr > (long)nrows - 1) mr = nrows - 1;

    bf16x8 a[4];
    if (IN_BF16) {
        const unsigned short* xb = (const unsigned short*)Xv + mr * 128 + lg * 8;
#pragma unroll
        for (int kt = 0; kt < 4; ++kt) a[kt] = *(const bf16x8*)(xb + kt * 32);
    } else {
        const float* xrow = (const float*)Xv + mr * 128 + lg * 8;
#pragma unroll
        for (int kt = 0; kt < 4; ++kt) {
            float4 lo = *(const float4*)(xrow + kt * 32);
            float4 hi = *(const float4*)(xrow + kt * 32 + 4);
            bf16x8 v;
            v[0] = (__bf16)lo.x; v[1] = (__bf16)lo.y; v[2] = (__bf16)lo.z; v[3] = (__bf16)lo.w;
            v[4] = (__bf16)hi.x; v[5] = (__bf16)hi.y; v[6] = (__bf16)hi.z; v[7] = (__bf16)hi.w;
            a[kt] = v;
        }
    }

    const bf16x8* Wf = (const bf16x8*)Wl;
    f32x4 acc[8];
#pragma unroll
    for (int nt = 0; nt < 8; ++nt) acc[nt] = (f32x4)(0.0f);
#pragma unroll
    for (int nt = 0; nt < 8; ++nt) {
#pragma unroll
        for (int kt = 0; kt < 4; ++kt)
            acc[nt] = __builtin_amdgcn_mfma_f32_16x16x32_bf16(a[kt], Wf[(nt * 4 + kt) * 64 + lane], acc[nt], 0, 0, 0);
    }

#pragma unroll
    for (int nt = 0; nt < 8; ++nt) {
        float b = Bias[nt * 16 + lr];
#pragma unroll
        for (int j = 0; j < 4; ++j) {
            long r = m0 + lg * 4 + j;
            if (r < nrows) {
                float s = rowscale ? rowscale[r] : 1.0f;
                Y[r * 128 + nt * 16 + lr] = f2bf(s * (acc[nt][j] + b));
            }
        }
    }
}

// ---------------- aggregation: premultiplied rows -> masked sum, scale by dinv[nd] ----------------

template<int OUT_BF16>
__global__ __launch_bounds__(256) void k_agg(const unsigned* __restrict__ hu, const float* __restrict__ dinv,
                                             const int* __restrict__ cntn, const int* __restrict__ start,
                                             const int* __restrict__ csrcol,
                                             void* __restrict__ outv, int n, int do_relu) {
    int wid = threadIdx.x >> 6, lane = threadIdx.x & 63;
    int nd = blockIdx.x * 4 + wid;
    if (nd >= n) return;
    float di = dinv[nd];
    unsigned v = hu[(long)nd * 64 + lane];   // h' self row (already dinv-scaled)
    float ax0 = bflo(v), ay0 = bfhi(v);
    float ax1 = 0.f, ay1 = 0.f;
    int m = cntn[nd];
    if (m > 0) {
        const int* cl = csrcol + start[nd];
        for (int j = 0; j < m; j += 8) {
            int c0 = cl[j];
            int c1 = cl[j + ((j + 1 < m) ? 1 : 0)];
            int c2 = cl[j + ((j + 2 < m) ? 2 : 0)];
            int c3 = cl[j + ((j + 3 < m) ? 3 : 0)];
            int c4 = cl[j + ((j + 4 < m) ? 4 : 0)];
            int c5 = cl[j + ((j + 5 < m) ? 5 : 0)];
            int c6 = cl[j + ((j + 6 < m) ? 6 : 0)];
            int c7 = cl[j + ((j + 7 < m) ? 7 : 0)];
            unsigned u0 = hu[(long)c0 * 64 + lane], u1 = hu[(long)c1 * 64 + lane];
            unsigned u2 = hu[(long)c2 * 64 + lane], u3 = hu[(long)c3 * 64 + lane];
            unsigned u4 = hu[(long)c4 * 64 + lane], u5 = hu[(long)c5 * 64 + lane];
            unsigned u6 = hu[(long)c6 * 64 + lane], u7 = hu[(long)c7 * 64 + lane];
            // mask out-of-range slots by zeroing the value (dup index -> L1 hit)
            unsigned m1 = (j + 1 < m) ? u1 : 0u;
            unsigned m2 = (j + 2 < m) ? u2 : 0u;
            unsigned m3 = (j + 3 < m) ? u3 : 0u;
            unsigned m4 = (j + 4 < m) ? u4 : 0u;
            unsigned m5 = (j + 5 < m) ? u5 : 0u;
            unsigned m6 = (j + 6 < m) ? u6 : 0u;
            unsigned m7 = (j + 7 < m) ? u7 : 0u;
            ax0 += bflo(u0); ay0 += bfhi(u0);
            ax1 += bflo(m1); ay1 += bfhi(m1);
            ax0 += bflo(m2); ay0 += bfhi(m2);
            ax1 += bflo(m3); ay1 += bfhi(m3);
            ax0 += bflo(m4); ay0 += bfhi(m4);
            ax1 += bflo(m5); ay1 += bfhi(m5);
            ax0 += bflo(m6); ay0 += bfhi(m6);
            ax1 += bflo(m7); ay1 += bfhi(m7);
        }
    }
    float ax = di * (ax0 + ax1);
    float ay = di * (ay0 + ay1);
    if (do_relu) { ax = fmaxf(ax, 0.f); ay = fmaxf(ay, 0.f); }
    if (OUT_BF16) {
        ((unsigned*)outv)[(long)nd * 64 + lane] = (unsigned)f2bf(ax) | ((unsigned)f2bf(ay) << 16);
    } else {
        float2 o; o.x = ax; o.y = ay;
        ((float2*)outv)[(long)nd * 64 + lane] = o;
    }
}

// ---------------- atomic-scatter fallback (unscaled h) ----------------

__global__ __launch_bounds__(256) void k_edge_deg_i(const int* __restrict__ col, int* degi, int ne) {
    int e = blockIdx.x * 256 + threadIdx.x;
    if (e >= ne) return;
    atomicAdd(&degi[col[e]], 1);
}

__global__ __launch_bounds__(256) void k_selfinit(const unsigned* __restrict__ hu, const float* __restrict__ dinv,
                                                  float* __restrict__ g, int n) {
    long i = (long)blockIdx.x * 256 + threadIdx.x;
    if (i >= (long)n * 64) return;
    int node = (int)(i >> 6);
    float d = dinv[node];
    unsigned u = hu[i];
    float2 o; o.x = d * d * bflo(u); o.y = d * d * bfhi(u);
    ((float2*)g)[i] = o;
}

__global__ __launch_bounds__(256) void k_scatter(const int* __restrict__ row, const int* __restrict__ col,
                                                 const float* __restrict__ dinv, const unsigned* __restrict__ hu,
                                                 float* __restrict__ g, int ne) {
    int e = blockIdx.x * 4 + (threadIdx.x >> 6);
    int lane = threadIdx.x & 63;
    if (e >= ne) return;
    int r = row[e], c = col[e];
    float nrm = dinv[r] * dinv[c];
    unsigned u = hu[(long)c * 64 + lane];
    atomicAdd(&g[(long)r * 128 + lane * 2], nrm * bflo(u));
    atomicAdd(&g[(long)r * 128 + lane * 2 + 1], nrm * bfhi(u));
}

__global__ __launch_bounds__(256) void k_reluf2bf(const float* __restrict__ g, unsigned* __restrict__ g16, long n2) {
    long i = (long)blockIdx.x * 256 + threadIdx.x;
    if (i >= n2) return;
    float2 v = ((const float2*)g)[i];
    g16[i] = (unsigned)f2bf(fmaxf(v.x, 0.f)) | ((unsigned)f2bf(fmaxf(v.y, 0.f)) << 16);
}

__global__ __launch_bounds__(256) void k_f32tobf(const float* __restrict__ g, unsigned* __restrict__ g16, long n2) {
    long i = (long)blockIdx.x * 256 + threadIdx.x;
    if (i >= n2) return;
    float2 v = ((const float2*)g)[i];
    g16[i] = (unsigned)f2bf(v.x) | ((unsigned)f2bf(v.y) << 16);
}

// ---------------- mean pool (two-stage, bf16 input) ----------------

__global__ __launch_bounds__(256) void k_pool_partial_bf16(const unsigned* __restrict__ g16,
                                                           const int* __restrict__ batch,
                                                           int n, float* __restrict__ partial, int* __restrict__ cntg) {
    int gid = blockIdx.x >> 3;
    int s   = blockIdx.x & 7;
    int t = threadIdx.x;
    int lo = 0, hi = n;
    while (lo < hi) { int m = (lo + hi) >> 1; if (batch[m] < gid) lo = m + 1; else hi = m; }
    int s0 = lo;
    hi = n;
    while (lo < hi) { int m = (lo + hi) >> 1; if (batch[m] < gid + 1) lo = m + 1; else hi = m; }
    int e0 = lo;
    if (s == 0 && t == 0) cntg[gid] = e0 - s0;

    int lane = t & 63, wid = t >> 6;
    float ax = 0.f, ay = 0.f;
    for (int i = s0 + s * 4 + wid; i < e0; i += 32) {
        unsigned u = g16[(long)i * 64 + lane];
        ax += bflo(u); ay += bfhi(u);
    }
    __shared__ float2 red[256];
    red[t] = make_float2(ax, ay);
    __syncthreads();
    if (t < 64) {
        float2 a = red[t];
#pragma unroll
        for (int r = 1; r < 4; ++r) {
            float2 b = red[r * 64 + t];
            a.x += b.x; a.y += b.y;
        }
        ((float2*)partial)[(long)blockIdx.x * 64 + t] = a;
    }
}

__global__ __launch_bounds__(256) void k_pool_final(const float* __restrict__ partial, const int* __restrict__ cntg,
                                                    int ng, float* __restrict__ out) {
    int idx = blockIdx.x * 256 + threadIdx.x;
    if (idx >= ng * 128) return;
    int gid = idx >> 7, col = idx & 127;
    float a = 0.f;
#pragma unroll
    for (int s = 0; s < POOL_S; ++s) a += partial[(long)(gid * POOL_S + s) * 128 + col];
    out[idx] = a / fmaxf((float)cntg[gid], 1.0f);
}

// ---------------- host ----------------

extern "C" void kernel_launch(void* const* d_in, const int* in_sizes, int n_in,
                              void* d_out, int out_size, void* d_ws, size_t ws_size,
                              hipStream_t stream) {
    const float* x  = (const float*)d_in[0];
    const int* ei   = (const int*)d_in[1];
    const int* batch = (const int*)d_in[2];
    const float* W1 = (const float*)d_in[4];
    const float* b1 = (const float*)d_in[5];
    const float* W2 = (const float*)d_in[6];
    const float* b2 = (const float*)d_in[7];

    int N = in_sizes[0] / 128;
    int E = in_sizes[1] / 2;
    const int* row = ei;
    const int* col = ei + E;
    int G = out_size / 128;
    int NBINS = (N + 511) >> BINB;

    char* ws = (char*)d_ws;
    size_t off = 0;
    auto alloc = [&](size_t bytes) -> void* {
        void* p = ws + off;
        off += (bytes + 255) & ~(size_t)255;
        return p;
    };
    int* degi   = (int*)alloc((size_t)N * 4);
    float* dinv = (float*)alloc((size_t)N * 4);
    unsigned short* h = (unsigned short*)alloc((size_t)N * 256);
    float* g    = (float*)alloc((size_t)N * 512);
    float* partial = (float*)alloc((size_t)G * POOL_S * 128 * 4);
    int* cntg   = (int*)alloc((size_t)G * 4);
    uint4* wp1  = (uint4*)alloc(32768);
    uint4* wp2  = (uint4*)alloc(32768);
    int* binFillR = (int*)alloc(1024);
    int* binFillC = (int*)alloc(1024);
    int* startA = (int*)alloc((size_t)N * 4);
    int* cntn   = (int*)alloc((size_t)N * 4);
    size_t segR_bytes = (size_t)NBINS * MAXPB * 4;
    size_t segC_bytes = (size_t)NBINS * MAXPB * 2;
    bool use_csr = (NBINS <= 256) && (off + 2 * segR_bytes + segC_bytes) <= ws_size;
    unsigned* sorted = use_csr ? (unsigned*)alloc(segR_bytes) : nullptr;
    unsigned short* sortedC = use_csr ? (unsigned short*)alloc(segC_bytes) : nullptr;
    int* csrcol = use_csr ? (int*)alloc(segR_bytes) : nullptr;

    int nbN = (N + 255) / 256;
    int gemm_blocks = (N + 63) / 64;
    int agg_blocks  = (N + 3) / 4;
    int scat_blocks = (E + EPB - 1) / EPB;

    k_prep<<<nbN, 256, 0, stream>>>(W1, W2, wp1, wp2, degi, binFillR, binFillC, N);

    if (use_csr) {
        k_binscat<<<scat_blocks, 256, 0, stream>>>(row, col, binFillR, binFillC, sorted, sortedC, E);
        k_csrdeg<<<2 * NBINS, 256, 0, stream>>>(sorted, binFillR, sortedC, binFillC,
                                                startA, cntn, csrcol, dinv, N, NBINS);
        // gemm writes h' = dinv[r]*(XW+b) -> agg is a plain masked sum scaled by dinv[nd]
        k_gemm_mfma<0><<<gemm_blocks, 256, 0, stream>>>(x, (const float4*)wp1, b1, dinv, h, N);
        k_agg<1><<<agg_blocks, 256, 0, stream>>>((const unsigned*)h, dinv, cntn, startA, csrcol, g, N, 1);
        k_gemm_mfma<1><<<gemm_blocks, 256, 0, stream>>>(g, (const float4*)wp2, b2, dinv, h, N);
        k_agg<1><<<agg_blocks, 256, 0, stream>>>((const unsigned*)h, dinv, cntn, startA, csrcol, g, N, 0);
        k_pool_partial_bf16<<<G * POOL_S, 256, 0, stream>>>((const unsigned*)g, batch, N, partial, cntg);
    } else {
        k_edge_deg_i<<<(E + 255) / 256, 256, 0, stream>>>(col, degi, E);
        k_dinv<<<nbN, 256, 0, stream>>>(degi, dinv, N);
        k_gemm_mfma<0><<<gemm_blocks, 256, 0, stream>>>(x, (const float4*)wp1, b1, nullptr, h, N);
        k_selfinit<<<(int)(((long)N * 64 + 255) / 256), 256, 0, stream>>>((const unsigned*)h, dinv, g, N);
        k_scatter<<<(E + 3) / 4, 256, 0, stream>>>(row, col, dinv, (const unsigned*)h, g, E);
        k_reluf2bf<<<(int)(((long)N * 64 + 255) / 256), 256, 0, stream>>>(g, (unsigned*)h, (long)N * 64);
        k_gemm_mfma<1><<<gemm_blocks, 256, 0, stream>>>(h, (const float4*)wp2, b2, nullptr, h, N);
        k_selfinit<<<(int)(((long)N * 64 + 255) / 256), 256, 0, stream>>>((const unsigned*)h, dinv, g, N);
        k_scatter<<<(E + 3) / 4, 256, 0, stream>>>(row, col, dinv, (const unsigned*)h, g, E);
        k_f32tobf<<<(int)(((long)N * 64 + 255) / 256), 256, 0, stream>>>(g, (unsigned*)g, (long)N * 64);
        k_pool_partial_bf16<<<G * POOL_S, 256, 0, stream>>>((const unsigned*)g, batch, N, partial, cntg);
    }

    k_pool_final<<<(G * 128 + 255) / 256, 256, 0, stream>>>(partial, cntg, G, (float*)d_out);
}

// Round 15
// 159.089 us; speedup vs baseline: 1.0344x; 1.0344x over previous
//
#include <hip/hip_runtime.h>

#define POOL_S 8
#define BINB 9
#define MAXPB 3584
#define EPB 2048

typedef __bf16 bf16x8 __attribute__((ext_vector_type(8)));
typedef float f32x4 __attribute__((ext_vector_type(4)));
typedef int intx4 __attribute__((ext_vector_type(4)));

__device__ __forceinline__ unsigned short f2bf(float f) {
    unsigned u = __float_as_uint(f);
    unsigned r = u + 0x7FFFu + ((u >> 16) & 1u);
    return (unsigned short)(r >> 16);
}
__device__ __forceinline__ float bflo(unsigned u) { return __uint_as_float(u << 16); }
__device__ __forceinline__ float bfhi(unsigned u) { return __uint_as_float(u & 0xFFFF0000u); }

// ---------------- W pre-pack ----------------

__device__ __forceinline__ void prepW_one(const float* __restrict__ W, uint4* __restrict__ Wp, int t) {
    int slot = t >> 6, lane = t & 63;
    int nt = slot >> 2, kt = slot & 3;
    int kbase = kt * 32 + (lane >> 4) * 8;
    int colw = nt * 16 + (lane & 15);
    unsigned short e[8];
#pragma unroll
    for (int j = 0; j < 8; ++j) e[j] = f2bf(W[(kbase + j) * 128 + colw]);
    uint4 v;
    v.x = e[0] | ((unsigned)e[1] << 16);
    v.y = e[2] | ((unsigned)e[3] << 16);
    v.z = e[4] | ((unsigned)e[5] << 16);
    v.w = e[6] | ((unsigned)e[7] << 16);
    Wp[t] = v;
}

__global__ __launch_bounds__(256) void k_prep(const float* __restrict__ W1, const float* __restrict__ W2,
                                              uint4* __restrict__ wp1, uint4* __restrict__ wp2,
                                              int* degi, int* binFillR, int* binFillC, int n) {
    int i = blockIdx.x * 256 + threadIdx.x;
    if (i < n) degi[i] = 0;
    if (i < 256) { binFillR[i] = 0; binFillC[i] = 0; }
    if (i < 2048) prepW_one(W1, wp1, i);
    else if (i < 4096) prepW_one(W2, wp2, i - 2048);
}

__global__ __launch_bounds__(256) void k_dinv(const int* __restrict__ degi, float* __restrict__ dinv, int n) {
    int i = blockIdx.x * 256 + threadIdx.x;
    if (i < n) dinv[i] = rsqrtf((float)degi[i] + 1.0f);   // +1: self loop
}

// ---------------- pass B: dual bin-scatter (rows -> CSR segs, cols -> deg segs) ----------------

__global__ __launch_bounds__(256) void k_binscat(const int* __restrict__ row, const int* __restrict__ col,
                                                 int* binFillR, int* binFillC,
                                                 unsigned* __restrict__ sortedR, unsigned short* __restrict__ sortedC,
                                                 int ne) {
    __shared__ int lhR[256], lbR[256], loR[256];
    __shared__ int lhC[256], lbC[256], loC[256];
    int t = threadIdx.x;
    lhR[t] = 0; loR[t] = 0; lhC[t] = 0; loC[t] = 0;
    __syncthreads();

    long base0 = (long)blockIdx.x * EPB + (long)t * 8;
    int r[8], c[8];
    int k = 0;
    if (base0 < ne) {
        k = (int)(ne - base0); if (k > 8) k = 8;
        if (k == 8) {
            intx4 r0 = *(const intx4*)(row + base0);
            intx4 r1 = *(const intx4*)(row + base0 + 4);
            intx4 c0 = *(const intx4*)(col + base0);
            intx4 c1 = *(const intx4*)(col + base0 + 4);
            r[0]=r0[0]; r[1]=r0[1]; r[2]=r0[2]; r[3]=r0[3];
            r[4]=r1[0]; r[5]=r1[1]; r[6]=r1[2]; r[7]=r1[3];
            c[0]=c0[0]; c[1]=c0[1]; c[2]=c0[2]; c[3]=c0[3];
            c[4]=c1[0]; c[5]=c1[1]; c[6]=c1[2]; c[7]=c1[3];
        } else {
            for (int i = 0; i < 8; ++i) { int e = i < k ? i : 0; r[i] = row[base0 + e]; c[i] = col[base0 + e]; }
        }
#pragma unroll
        for (int i = 0; i < 8; ++i) if (i < k) {
            atomicAdd(&lhR[r[i] >> BINB], 1);
            atomicAdd(&lhC[c[i] >> BINB], 1);
        }
    }
    __syncthreads();
    if (lhR[t] > 0) lbR[t] = atomicAdd(&binFillR[t], lhR[t]);
    if (lhC[t] > 0) lbC[t] = atomicAdd(&binFillC[t], lhC[t]);
    __syncthreads();
#pragma unroll
    for (int i = 0; i < 8; ++i) if (i < k) {
        int bR = r[i] >> BINB;
        int p = lbR[bR] + atomicAdd(&loR[bR], 1);
        if (p < MAXPB) sortedR[(long)bR * MAXPB + p] = ((unsigned)(r[i] & 511) << 17) | (unsigned)c[i];
        int bC = c[i] >> BINB;
        int q = lbC[bC] + atomicAdd(&loC[bC], 1);
        if (q < MAXPB) sortedC[(long)bC * MAXPB + q] = (unsigned short)(c[i] & 511);
    }
}

// ---------------- pass C: blocks [0,nbins) build row-CSR; [nbins,2*nbins) build dinv ----------------

__global__ __launch_bounds__(256) void k_csrdeg(const unsigned* __restrict__ sortedR, const int* __restrict__ binFillR,
                                                const unsigned short* __restrict__ sortedC, const int* __restrict__ binFillC,
                                                int* __restrict__ start, int* __restrict__ cntn,
                                                int* __restrict__ csrcol, float* __restrict__ dinv,
                                                int n, int nbins) {
    __shared__ int lcnt[512];
    __shared__ int lex[512];
    __shared__ int ps[256];
    __shared__ int lcsr[MAXPB];
    int t = threadIdx.x;

    if ((int)blockIdx.x >= nbins) {
        int bc = blockIdx.x - nbins;
        lcnt[t] = 0; lcnt[t + 256] = 0;
        __syncthreads();
        int cntE = binFillC[bc]; if (cntE > MAXPB) cntE = MAXPB;
        long base = (long)bc * MAXPB;
        for (int e = t; e < cntE; e += 256) atomicAdd(&lcnt[sortedC[base + e]], 1);
        __syncthreads();
        int nd0 = (bc << BINB) + t, nd1 = nd0 + 256;
        if (nd0 < n) dinv[nd0] = rsqrtf((float)lcnt[t] + 1.0f);
        if (nd1 < n) dinv[nd1] = rsqrtf((float)lcnt[t + 256] + 1.0f);
        return;
    }

    int b = blockIdx.x;
    int node0 = b << BINB;
    int cntE = binFillR[b]; if (cntE > MAXPB) cntE = MAXPB;
    long base = (long)b * MAXPB;

    lcnt[t] = 0; lcnt[t + 256] = 0;
    __syncthreads();
    for (int e = t; e < cntE; e += 256) atomicAdd(&lcnt[sortedR[base + e] >> 17], 1);
    __syncthreads();

    int a0 = lcnt[2 * t], a1 = lcnt[2 * t + 1];
    ps[t] = a0 + a1;
    __syncthreads();
    for (int d = 1; d < 256; d <<= 1) {
        int u = (t >= d) ? ps[t - d] : 0;
        __syncthreads();
        ps[t] += u;
        __syncthreads();
    }
    int excl_pair = ps[t] - (a0 + a1);
    lex[2 * t] = excl_pair;
    lex[2 * t + 1] = excl_pair + a0;
    __syncthreads();

    int nd0 = node0 + t, nd1 = node0 + t + 256;
    if (nd0 < n) { start[nd0] = (int)base + lex[t];       cntn[nd0] = lcnt[t]; }
    if (nd1 < n) { start[nd1] = (int)base + lex[t + 256]; cntn[nd1] = lcnt[t + 256]; }
    __syncthreads();
    lcnt[t] = lex[t]; lcnt[t + 256] = lex[t + 256];
    __syncthreads();
    for (int e = t; e < cntE; e += 256) {
        unsigned pk = sortedR[base + e];
        int lr = (int)(pk >> 17);
        int pos = atomicAdd(&lcnt[lr], 1);
        lcsr[pos] = (int)(pk & 0x1FFFFu);
    }
    __syncthreads();
    for (int e = t; e < cntE; e += 256) csrcol[base + e] = lcsr[e];
}

// ---------------- GEMM: 64 rows x 128 cols per block; optional per-row scale (dinv) ----------------

template<int IN_BF16>
__global__ __launch_bounds__(256) void k_gemm_mfma(const void* __restrict__ Xv,
        const float4* __restrict__ Wp, const float* __restrict__ Bias,
        const float* __restrict__ rowscale,
        unsigned short* __restrict__ Y, int nrows) {
    __shared__ float4 Wl[2048];
    int t = threadIdx.x;
#pragma unroll
    for (int i = 0; i < 8; ++i) Wl[t + 256 * i] = Wp[t + 256 * i];
    __syncthreads();

    int wid = t >> 6, lane = t & 63;
    long m0 = ((long)blockIdx.x * 4 + wid) * 16;
    if (m0 >= nrows) return;
    int lr = lane & 15, lg = lane >> 4;
    long mr = m0 + lr; if (mr > (long)nrows - 1) mr = nrows - 1;

    bf16x8 a[4];
    if (IN_BF16) {
        const unsigned short* xb = (const unsigned short*)Xv + mr * 128 + lg * 8;
#pragma unroll
        for (int kt = 0; kt < 4; ++kt) a[kt] = *(const bf16x8*)(xb + kt * 32);
    } else {
        const float* xrow = (const float*)Xv + mr * 128 + lg * 8;
#pragma unroll
        for (int kt = 0; kt < 4; ++kt) {
            float4 lo = *(const float4*)(xrow + kt * 32);
            float4 hi = *(const float4*)(xrow + kt * 32 + 4);
            bf16x8 v;
            v[0] = (__bf16)lo.x; v[1] = (__bf16)lo.y; v[2] = (__bf16)lo.z; v[3] = (__bf16)lo.w;
            v[4] = (__bf16)hi.x; v[5] = (__bf16)hi.y; v[6] = (__bf16)hi.z; v[7] = (__bf16)hi.w;
            a[kt] = v;
        }
    }

    const bf16x8* Wf = (const bf16x8*)Wl;
    f32x4 acc[8];
#pragma unroll
    for (int nt = 0; nt < 8; ++nt) acc[nt] = (f32x4)(0.0f);
#pragma unroll
    for (int nt = 0; nt < 8; ++nt) {
#pragma unroll
        for (int kt = 0; kt < 4; ++kt)
            acc[nt] = __builtin_amdgcn_mfma_f32_16x16x32_bf16(a[kt], Wf[(nt * 4 + kt) * 64 + lane], acc[nt], 0, 0, 0);
    }

#pragma unroll
    for (int nt = 0; nt < 8; ++nt) {
        float b = Bias[nt * 16 + lr];
#pragma unroll
        for (int j = 0; j < 4; ++j) {
            long r = m0 + lg * 4 + j;
            if (r < nrows) {
                float s = rowscale ? rowscale[r] : 1.0f;
                Y[r * 128 + nt * 16 + lr] = f2bf(s * (acc[nt][j] + b));
            }
        }
    }
}

// ---------------- aggregation: 2 nodes per wave (uint2 lanes), premultiplied rows ----------------
// SAFETY: all csrcol reads use position p<m (clamped); m==0 threads substitute c=nd.

template<int OUT_BF16>
__global__ __launch_bounds__(256) void k_agg(const uint2* __restrict__ hu2, const float* __restrict__ dinv,
                                             const int* __restrict__ cntn, const int* __restrict__ start,
                                             const int* __restrict__ csrcol,
                                             void* __restrict__ outv, int n, int do_relu) {
    int t = threadIdx.x;
    int wid = t >> 6, lane = t & 63;
    int half = lane >> 5;          // which node in the wave
    int cp = lane & 31;            // 8B col-pair index within the 256B row
    int ndr = blockIdx.x * 8 + wid * 2 + half;
    bool valid = ndr < n;
    int nd = valid ? ndr : (n - 1);
    float di = dinv[nd];
    uint2 v = hu2[(long)nd * 32 + cp];     // self row (already dinv-scaled)
    float a0 = bflo(v.x), a1 = bfhi(v.x), a2 = bflo(v.y), a3 = bfhi(v.y);
    float b0 = 0.f, b1 = 0.f, b2 = 0.f, b3 = 0.f;
    int m = cntn[nd];
    int mo = __shfl_xor(m, 32);
    int mmax = m > mo ? m : mo;
    if (mmax > 0) {
        const int* cl = csrcol + start[nd];
        bool has = (m > 0);
        for (int j = 0; j < mmax; j += 8) {
            int p0 = (j + 0 < m) ? j + 0 : 0;
            int p1 = (j + 1 < m) ? j + 1 : 0;
            int p2 = (j + 2 < m) ? j + 2 : 0;
            int p3 = (j + 3 < m) ? j + 3 : 0;
            int p4 = (j + 4 < m) ? j + 4 : 0;
            int p5 = (j + 5 < m) ? j + 5 : 0;
            int p6 = (j + 6 < m) ? j + 6 : 0;
            int p7 = (j + 7 < m) ? j + 7 : 0;
            int c0 = has ? cl[p0] : nd;
            int c1 = has ? cl[p1] : nd;
            int c2 = has ? cl[p2] : nd;
            int c3 = has ? cl[p3] : nd;
            int c4 = has ? cl[p4] : nd;
            int c5 = has ? cl[p5] : nd;
            int c6 = has ? cl[p6] : nd;
            int c7 = has ? cl[p7] : nd;
            uint2 u0 = hu2[(long)c0 * 32 + cp], u1 = hu2[(long)c1 * 32 + cp];
            uint2 u2 = hu2[(long)c2 * 32 + cp], u3 = hu2[(long)c3 * 32 + cp];
            uint2 u4 = hu2[(long)c4 * 32 + cp], u5 = hu2[(long)c5 * 32 + cp];
            uint2 u6 = hu2[(long)c6 * 32 + cp], u7 = hu2[(long)c7 * 32 + cp];
            if (j + 0 >= m) { u0.x = 0; u0.y = 0; }
            if (j + 1 >= m) { u1.x = 0; u1.y = 0; }
            if (j + 2 >= m) { u2.x = 0; u2.y = 0; }
            if (j + 3 >= m) { u3.x = 0; u3.y = 0; }
            if (j + 4 >= m) { u4.x = 0; u4.y = 0; }
            if (j + 5 >= m) { u5.x = 0; u5.y = 0; }
            if (j + 6 >= m) { u6.x = 0; u6.y = 0; }
            if (j + 7 >= m) { u7.x = 0; u7.y = 0; }
            a0 += bflo(u0.x); a1 += bfhi(u0.x); a2 += bflo(u0.y); a3 += bfhi(u0.y);
            b0 += bflo(u1.x); b1 += bfhi(u1.x); b2 += bflo(u1.y); b3 += bfhi(u1.y);
            a0 += bflo(u2.x); a1 += bfhi(u2.x); a2 += bflo(u2.y); a3 += bfhi(u2.y);
            b0 += bflo(u3.x); b1 += bfhi(u3.x); b2 += bflo(u3.y); b3 += bfhi(u3.y);
            a0 += bflo(u4.x); a1 += bfhi(u4.x); a2 += bflo(u4.y); a3 += bfhi(u4.y);
            b0 += bflo(u5.x); b1 += bfhi(u5.x); b2 += bflo(u5.y); b3 += bfhi(u5.y);
            a0 += bflo(u6.x); a1 += bfhi(u6.x); a2 += bflo(u6.y); a3 += bfhi(u6.y);
            b0 += bflo(u7.x); b1 += bfhi(u7.x); b2 += bflo(u7.y); b3 += bfhi(u7.y);
        }
    }
    float s0 = di * (a0 + b0);
    float s1 = di * (a1 + b1);
    float s2 = di * (a2 + b2);
    float s3 = di * (a3 + b3);
    if (do_relu) {
        s0 = fmaxf(s0, 0.f); s1 = fmaxf(s1, 0.f);
        s2 = fmaxf(s2, 0.f); s3 = fmaxf(s3, 0.f);
    }
    if (!valid) return;
    if (OUT_BF16) {
        uint2 o;
        o.x = (unsigned)f2bf(s0) | ((unsigned)f2bf(s1) << 16);
        o.y = (unsigned)f2bf(s2) | ((unsigned)f2bf(s3) << 16);
        ((uint2*)outv)[(long)nd * 32 + cp] = o;
    } else {
        float4 o; o.x = s0; o.y = s1; o.z = s2; o.w = s3;
        ((float4*)outv)[(long)nd * 32 + cp] = o;
    }
}

// ---------------- atomic-scatter fallback (unscaled h) ----------------

__global__ __launch_bounds__(256) void k_edge_deg_i(const int* __restrict__ col, int* degi, int ne) {
    int e = blockIdx.x * 256 + threadIdx.x;
    if (e >= ne) return;
    atomicAdd(&degi[col[e]], 1);
}

__global__ __launch_bounds__(256) void k_selfinit(const unsigned* __restrict__ hu, const float* __restrict__ dinv,
                                                  float* __restrict__ g, int n) {
    long i = (long)blockIdx.x * 256 + threadIdx.x;
    if (i >= (long)n * 64) return;
    int node = (int)(i >> 6);
    float d = dinv[node];
    unsigned u = hu[i];
    float2 o; o.x = d * d * bflo(u); o.y = d * d * bfhi(u);
    ((float2*)g)[i] = o;
}

__global__ __launch_bounds__(256) void k_scatter(const int* __restrict__ row, const int* __restrict__ col,
                                                 const float* __restrict__ dinv, const unsigned* __restrict__ hu,
                                                 float* __restrict__ g, int ne) {
    int e = blockIdx.x * 4 + (threadIdx.x >> 6);
    int lane = threadIdx.x & 63;
    if (e >= ne) return;
    int r = row[e], c = col[e];
    float nrm = dinv[r] * dinv[c];
    unsigned u = hu[(long)c * 64 + lane];
    atomicAdd(&g[(long)r * 128 + lane * 2], nrm * bflo(u));
    atomicAdd(&g[(long)r * 128 + lane * 2 + 1], nrm * bfhi(u));
}

__global__ __launch_bounds__(256) void k_reluf2bf(const float* __restrict__ g, unsigned* __restrict__ g16, long n2) {
    long i = (long)blockIdx.x * 256 + threadIdx.x;
    if (i >= n2) return;
    float2 v = ((const float2*)g)[i];
    g16[i] = (unsigned)f2bf(fmaxf(v.x, 0.f)) | ((unsigned)f2bf(fmaxf(v.y, 0.f)) << 16);
}

__global__ __launch_bounds__(256) void k_f32tobf(const float* __restrict__ g, unsigned* __restrict__ g16, long n2) {
    long i = (long)blockIdx.x * 256 + threadIdx.x;
    if (i >= n2) return;
    float2 v = ((const float2*)g)[i];
    g16[i] = (unsigned)f2bf(v.x) | ((unsigned)f2bf(v.y) << 16);
}

// ---------------- mean pool (two-stage, bf16 input) ----------------

__global__ __launch_bounds__(256) void k_pool_partial_bf16(const unsigned* __restrict__ g16,
                                                           const int* __restrict__ batch,
                                                           int n, float* __restrict__ partial, int* __restrict__ cntg) {
    int gid = blockIdx.x >> 3;
    int s   = blockIdx.x & 7;
    int t = threadIdx.x;
    int lo = 0, hi = n;
    while (lo < hi) { int m = (lo + hi) >> 1; if (batch[m] < gid) lo = m + 1; else hi = m; }
    int s0 = lo;
    hi = n;
    while (lo < hi) { int m = (lo + hi) >> 1; if (batch[m] < gid + 1) lo = m + 1; else hi = m; }
    int e0 = lo;
    if (s == 0 && t == 0) cntg[gid] = e0 - s0;

    int lane = t & 63, wid = t >> 6;
    float ax = 0.f, ay = 0.f;
    for (int i = s0 + s * 4 + wid; i < e0; i += 32) {
        unsigned u = g16[(long)i * 64 + lane];
        ax += bflo(u); ay += bfhi(u);
    }
    __shared__ float2 red[256];
    red[t] = make_float2(ax, ay);
    __syncthreads();
    if (t < 64) {
        float2 a = red[t];
#pragma unroll
        for (int r = 1; r < 4; ++r) {
            float2 b = red[r * 64 + t];
            a.x += b.x; a.y += b.y;
        }
        ((float2*)partial)[(long)blockIdx.x * 64 + t] = a;
    }
}

__global__ __launch_bounds__(256) void k_pool_final(const float* __restrict__ partial, const int* __restrict__ cntg,
                                                    int ng, float* __restrict__ out) {
    int idx = blockIdx.x * 256 + threadIdx.x;
    if (idx >= ng * 128) return;
    int gid = idx >> 7, col = idx & 127;
    float a = 0.f;
#pragma unroll
    for (int s = 0; s < POOL_S; ++s) a += partial[(long)(gid * POOL_S + s) * 128 + col];
    out[idx] = a / fmaxf((float)cntg[gid], 1.0f);
}

// ---------------- host ----------------

extern "C" void kernel_launch(void* const* d_in, const int* in_sizes, int n_in,
                              void* d_out, int out_size, void* d_ws, size_t ws_size,
                              hipStream_t stream) {
    const float* x  = (const float*)d_in[0];
    const int* ei   = (const int*)d_in[1];
    const int* batch = (const int*)d_in[2];
    const float* W1 = (const float*)d_in[4];
    const float* b1 = (const float*)d_in[5];
    const float* W2 = (const float*)d_in[6];
    const float* b2 = (const float*)d_in[7];

    int N = in_sizes[0] / 128;
    int E = in_sizes[1] / 2;
    const int* row = ei;
    const int* col = ei + E;
    int G = out_size / 128;
    int NBINS = (N + 511) >> BINB;

    char* ws = (char*)d_ws;
    size_t off = 0;
    auto alloc = [&](size_t bytes) -> void* {
        void* p = ws + off;
        off += (bytes + 255) & ~(size_t)255;
        return p;
    };
    int* degi   = (int*)alloc((size_t)N * 4);
    float* dinv = (float*)alloc((size_t)N * 4);
    unsigned short* h = (unsigned short*)alloc((size_t)N * 256);
    float* g    = (float*)alloc((size_t)N * 512);
    float* partial = (float*)alloc((size_t)G * POOL_S * 128 * 4);
    int* cntg   = (int*)alloc((size_t)G * 4);
    uint4* wp1  = (uint4*)alloc(32768);
    uint4* wp2  = (uint4*)alloc(32768);
    int* binFillR = (int*)alloc(1024);
    int* binFillC = (int*)alloc(1024);
    int* startA = (int*)alloc((size_t)N * 4);
    int* cntn   = (int*)alloc((size_t)N * 4);
    size_t segR_bytes = (size_t)NBINS * MAXPB * 4;
    size_t segC_bytes = (size_t)NBINS * MAXPB * 2;
    bool use_csr = (NBINS <= 256) && (off + 2 * segR_bytes + segC_bytes + 512) <= ws_size;
    unsigned* sorted = use_csr ? (unsigned*)alloc(segR_bytes) : nullptr;
    unsigned short* sortedC = use_csr ? (unsigned short*)alloc(segC_bytes) : nullptr;
    int* csrcol = use_csr ? (int*)alloc(segR_bytes + 256) : nullptr;

    int nbN = (N + 255) / 256;
    int gemm_blocks = (N + 63) / 64;
    int agg_blocks  = (N + 7) / 8;
    int scat_blocks = (E + EPB - 1) / EPB;

    k_prep<<<nbN, 256, 0, stream>>>(W1, W2, wp1, wp2, degi, binFillR, binFillC, N);

    if (use_csr) {
        k_binscat<<<scat_blocks, 256, 0, stream>>>(row, col, binFillR, binFillC, sorted, sortedC, E);
        k_csrdeg<<<2 * NBINS, 256, 0, stream>>>(sorted, binFillR, sortedC, binFillC,
                                                startA, cntn, csrcol, dinv, N, NBINS);
        // gemm writes h' = dinv[r]*(XW+b) -> agg is a plain masked sum scaled by dinv[nd]
        k_gemm_mfma<0><<<gemm_blocks, 256, 0, stream>>>(x, (const float4*)wp1, b1, dinv, h, N);
        k_agg<1><<<agg_blocks, 256, 0, stream>>>((const uint2*)h, dinv, cntn, startA, csrcol, g, N, 1);
        k_gemm_mfma<1><<<gemm_blocks, 256, 0, stream>>>(g, (const float4*)wp2, b2, dinv, h, N);
        k_agg<1><<<agg_blocks, 256, 0, stream>>>((const uint2*)h, dinv, cntn, startA, csrcol, g, N, 0);
        k_pool_partial_bf16<<<G * POOL_S, 256, 0, stream>>>((const unsigned*)g, batch, N, partial, cntg);
    } else {
        k_edge_deg_i<<<(E + 255) / 256, 256, 0, stream>>>(col, degi, E);
        k_dinv<<<nbN, 256, 0, stream>>>(degi, dinv, N);
        k_gemm_mfma<0><<<gemm_blocks, 256, 0, stream>>>(x, (const float4*)wp1, b1, nullptr, h, N);
        k_selfinit<<<(int)(((long)N * 64 + 255) / 256), 256, 0, stream>>>((const unsigned*)h, dinv, g, N);
        k_scatter<<<(E + 3) / 4, 256, 0, stream>>>(row, col, dinv, (const unsigned*)h, g, E);
        k_reluf2bf<<<(int)(((long)N * 64 + 255) / 256), 256, 0, stream>>>(g, (unsigned*)h, (long)N * 64);
        k_gemm_mfma<1><<<gemm_blocks, 256, 0, stream>>>(h, (const float4*)wp2, b2, nullptr, h, N);
        k_selfinit<<<(int)(((long)N * 64 + 255) / 256), 256, 0, stream>>>((const unsigned*)h, dinv, g, N);
        k_scatter<<<(E + 3) / 4, 256, 0, stream>>>(row, col, dinv, (const unsigned*)h, g, E);
        k_f32tobf<<<(int)(((long)N * 64 + 255) / 256), 256, 0, stream>>>(g, (unsigned*)g, (long)N * 64);
        k_pool_partial_bf16<<<G * POOL_S, 256, 0, stream>>>((const unsigned*)g, batch, N, partial, cntg);
    }

    k_pool_final<<<(G * 128 + 255) / 256, 256, 0, stream>>>(partial, cntg, G, (float*)d_out);
}